// Round 1
// baseline (279.834 us; speedup 1.0000x reference)
//
#include <hip/hip_runtime.h>
#include <cstdint>
#include <cstddef>

// ---------------------------------------------------------------------------
// NeighborTransferModel fused pipeline for MI355X (gfx950)
//
// Key algebraic optimization: feature vector is [qp, np, qp-np, qd, nd, qd-nd,
// aff, ppr, trust, sim].  f @ W1 decomposes into query-side and neighbor-side
// GEMMs with folded weights:
//   neighbor coeffs:  np: W1[1024+j] - W1[2048+j];  nd: W1[3584+j] - W1[4096+j]
//   query    coeffs:  qp: W1[j] + W1[2048+j];       qd: W1[3072+j] + W1[4096+j]
// Both MLPs (weight_net, delta_net) fused into one 512-wide GEMM; binding
// encoder fused into the query GEMM (cols 512..767).
// ---------------------------------------------------------------------------

typedef __attribute__((ext_vector_type(8))) short s16x8;
typedef __attribute__((ext_vector_type(4))) float f32x4;

static __device__ __forceinline__ unsigned short f2bf(float f) {
  unsigned u = __float_as_uint(f);
  u += 0x7fffu + ((u >> 16) & 1u);   // round-to-nearest-even
  return (unsigned short)(u >> 16);
}
static __device__ __forceinline__ float bf2f(unsigned short h) {
  return __uint_as_float(((unsigned)h) << 16);
}

// ---------------------------------------------------------------------------
// Weight-fold kernel: build bf16 B^T matrices.
//   Bt1 [512][1536]  neighbor-side folded (cols 0..255 w1, 256..511 d1)
//   Btq [768][1536]  query-side folded (0..255 w1, 256..511 d1, 512..767 be1)
//   Bt2 [256][512]   block-diagonal layer-2 (0..127 w2, 128..255 d2)
// ---------------------------------------------------------------------------
__global__ void prepw_k(const float* __restrict__ w1, const float* __restrict__ d1,
                        const float* __restrict__ be1, const float* __restrict__ w2,
                        const float* __restrict__ d2,
                        unsigned short* __restrict__ Bt1,
                        unsigned short* __restrict__ Btq,
                        unsigned short* __restrict__ Bt2) {
  const int NB1 = 512 * 1536, NBQ = 768 * 1536, NB2 = 256 * 512;
  for (int idx = blockIdx.x * 256 + threadIdx.x; idx < NB1 + NBQ + NB2;
       idx += gridDim.x * 256) {
    if (idx < NB1) {
      int c = idx / 1536, j = idx - c * 1536;
      const float* W = (c < 256) ? w1 : d1;
      int cc = c & 255;
      float v;
      if (j < 1024) v = W[(1024 + j) * 256 + cc] - W[(2048 + j) * 256 + cc];
      else { int jd = j - 1024; v = W[(3584 + jd) * 256 + cc] - W[(4096 + jd) * 256 + cc]; }
      Bt1[idx] = f2bf(v);
    } else if (idx < NB1 + NBQ) {
      int i2 = idx - NB1;
      int c = i2 / 1536, j = i2 - c * 1536;
      float v;
      if (c < 512) {
        const float* W = (c < 256) ? w1 : d1;
        int cc = c & 255;
        if (j < 1024) v = W[j * 256 + cc] + W[(2048 + j) * 256 + cc];
        else { int jd = j - 1024; v = W[(3072 + jd) * 256 + cc] + W[(4096 + jd) * 256 + cc]; }
      } else {
        v = be1[j * 256 + (c - 512)];
      }
      Btq[i2] = f2bf(v);
    } else {
      int i2 = idx - NB1 - NBQ;
      int c = i2 / 512, j = i2 - c * 512;
      float v = 0.f;
      if (c < 128 && j < 256) v = w2[j * 128 + c];
      else if (c >= 128 && j >= 256) v = d2[(j - 256) * 128 + (c - 128)];
      Bt2[i2] = f2bf(v);
    }
  }
}

// ---------------------------------------------------------------------------
// Query prep: Aq bf16 [1024][1536] = [qp | qd], qn[n] = ||qd_n||
// ---------------------------------------------------------------------------
__global__ void qprep_k(const float* __restrict__ qp, const float* __restrict__ qd,
                        unsigned short* __restrict__ Aq, float* __restrict__ qn) {
  int n = blockIdx.x, t = threadIdx.x;
  const float4* qp4 = (const float4*)(qp + (size_t)n * 1024);
  float4 v = qp4[t];
  ushort4 o4;
  o4.x = f2bf(v.x); o4.y = f2bf(v.y); o4.z = f2bf(v.z); o4.w = f2bf(v.w);
  *(ushort4*)(Aq + (size_t)n * 1536 + t * 4) = o4;
  const float2* qd2 = (const float2*)(qd + (size_t)n * 512);
  float2 w = qd2[t];
  ushort2 o2; o2.x = f2bf(w.x); o2.y = f2bf(w.y);
  *(ushort2*)(Aq + (size_t)n * 1536 + 1024 + t * 2) = o2;
  float ss = w.x * w.x + w.y * w.y;
  #pragma unroll
  for (int m = 32; m >= 1; m >>= 1) ss += __shfl_xor(ss, m);
  __shared__ float sr[4];
  if ((t & 63) == 0) sr[t >> 6] = ss;
  __syncthreads();
  if (t == 0) qn[n] = sqrtf(sr[0] + sr[1] + sr[2] + sr[3]);
}

// ---------------------------------------------------------------------------
// Cosine similarity: sim[r] for r = n*32+k  (one wave per row)
// ---------------------------------------------------------------------------
__global__ void simk_k(const float* __restrict__ nd, const float* __restrict__ qd,
                       const float* __restrict__ qn, float* __restrict__ sim) {
  int r = blockIdx.x * 4 + (threadIdx.x >> 6);
  int l = threadIdx.x & 63;
  int n = r >> 5;
  const float4* a = (const float4*)(nd + (size_t)r * 512);
  const float4* b = (const float4*)(qd + (size_t)n * 512);
  float dot = 0.f, ns = 0.f;
  #pragma unroll
  for (int j = 0; j < 2; ++j) {
    float4 x = a[l + 64 * j], y = b[l + 64 * j];
    dot += x.x * y.x + x.y * y.y + x.z * y.z + x.w * y.w;
    ns  += x.x * x.x + x.y * x.y + x.z * x.z + x.w * x.w;
  }
  #pragma unroll
  for (int m = 32; m >= 1; m >>= 1) { dot += __shfl_xor(dot, m); ns += __shfl_xor(ns, m); }
  if (l == 0) sim[r] = dot / (fmaxf(qn[n], 1e-8f) * fmaxf(sqrtf(ns), 1e-8f));
}

// ---------------------------------------------------------------------------
// Generic 128x128 bf16 MFMA GEMM (BK=64, XOR-swizzled LDS, fused epilogues)
// MODE 0: query GEMM   M=1024,  Kd=1536, NC=768, A=Aq bf16 -> uq fp32 (+bias)
// MODE 1: neighbor GEMM M=32768, Kd=1536, NC=512, A=(np|nd) fp32 -> h1 bf16
//         epilogue: relu(acc + uq[n,c] + aff*S0 + ppr*S1 + trust*S2 + sim*S3)
// MODE 2: layer-2 GEMM M=32768, Kd=512,  NC=256, A=h1 bf16 -> h2 bf16 (relu+bias)
// ---------------------------------------------------------------------------
struct GArgs {
  const float* a1; const float* a2;        // MODE1 fp32 pieces (widths 1024 / 512)
  const unsigned short* abf;               // MODE0/2 bf16 A (row stride Kd)
  const unsigned short* Bt;                // [NC][Kd] bf16
  float* uq_out;
  const float* wb1; const float* db1; const float* beb1;
  const float* uq_in; const float* aff; const float* ppr; const float* trs; const float* sim;
  const float* w1; const float* d1;
  unsigned short* h_out;
  const float* wb2; const float* db2;
};

template <int MODE>
__global__ __launch_bounds__(256) void gemm_k(GArgs A) {
  constexpr int Kd = (MODE == 2) ? 512 : 1536;
  constexpr int KSTEPS = Kd / 64;
  __shared__ short As[128 * 64];
  __shared__ short Bs[128 * 64];
  const int tid = threadIdx.x;
  const int l = tid & 63, w = tid >> 6;
  const int wr = w >> 1, wc = w & 1;
  const int br = blockIdx.x, bc = blockIdx.y;
  const int c0 = bc * 128;
  f32x4 acc[4][4] = {};

  for (int kt = 0; kt < KSTEPS; ++kt) {
    const int k0 = kt * 64;
    __syncthreads();
    // ---- stage A and B tiles into LDS, XOR-swizzled: LDS[row][slot] holds
    //      global k-chunk (slot ^ (row&7)), 8 bf16 per 16B chunk ----
    #pragma unroll
    for (int rep = 0; rep < 4; ++rep) {
      int q = rep * 256 + tid;
      int row = q >> 3, slot = q & 7;
      int kc = slot ^ (row & 7);
      int gk = k0 + kc * 8;
      long grow = (long)br * 128 + row;
      s16x8 pk;
      if constexpr (MODE == 1) {
        const float* src = (gk < 1024) ? (A.a1 + grow * 1024 + gk)
                                       : (A.a2 + grow * 512 + (gk - 1024));
        float4 v0 = ((const float4*)src)[0];
        float4 v1 = ((const float4*)src)[1];
        pk[0] = (short)f2bf(v0.x); pk[1] = (short)f2bf(v0.y);
        pk[2] = (short)f2bf(v0.z); pk[3] = (short)f2bf(v0.w);
        pk[4] = (short)f2bf(v1.x); pk[5] = (short)f2bf(v1.y);
        pk[6] = (short)f2bf(v1.z); pk[7] = (short)f2bf(v1.w);
      } else {
        pk = *(const s16x8*)(A.abf + grow * Kd + gk);
      }
      *(s16x8*)(&As[q * 8]) = pk;
      s16x8 pb = *(const s16x8*)(A.Bt + (long)(c0 + row) * Kd + gk);
      *(s16x8*)(&Bs[q * 8]) = pb;
    }
    __syncthreads();
    // ---- MFMA: 2 k-halves x 4x4 fragments of 16x16x32 ----
    #pragma unroll
    for (int kh = 0; kh < 2; ++kh) {
      s16x8 af[4], bfr[4];
      #pragma unroll
      for (int mi = 0; mi < 4; ++mi) {
        int ra = wr * 64 + mi * 16 + (l & 15);
        int sidx = (kh * 4 + (l >> 4)) ^ (ra & 7);
        af[mi] = *(const s16x8*)(&As[ra * 64 + sidx * 8]);
      }
      #pragma unroll
      for (int ni = 0; ni < 4; ++ni) {
        int rb = wc * 64 + ni * 16 + (l & 15);
        int sidx = (kh * 4 + (l >> 4)) ^ (rb & 7);
        bfr[ni] = *(const s16x8*)(&Bs[rb * 64 + sidx * 8]);
      }
      #pragma unroll
      for (int mi = 0; mi < 4; ++mi)
        #pragma unroll
        for (int ni = 0; ni < 4; ++ni)
          acc[mi][ni] = __builtin_amdgcn_mfma_f32_16x16x32_bf16(
              af[mi], bfr[ni], acc[mi][ni], 0, 0, 0);
    }
  }

  // ---- epilogue; C/D map: row = (l>>4)*4 + r, col = l&15 ----
  #pragma unroll
  for (int mi = 0; mi < 4; ++mi) {
    #pragma unroll
    for (int ni = 0; ni < 4; ++ni) {
      #pragma unroll
      for (int r = 0; r < 4; ++r) {
        int rowl = wr * 64 + mi * 16 + (l >> 4) * 4 + r;
        int coll = wc * 64 + ni * 16 + (l & 15);
        long grow = (long)br * 128 + rowl;
        int gcol = c0 + coll;
        float v = acc[mi][ni][r];
        if constexpr (MODE == 0) {
          float b = (gcol < 256) ? A.wb1[gcol]
                   : (gcol < 512) ? A.db1[gcol - 256] : A.beb1[gcol - 512];
          A.uq_out[grow * 768 + gcol] = v + b;
        } else if constexpr (MODE == 1) {
          long n = grow >> 5;
          const float* W = (gcol < 256) ? A.w1 : A.d1;
          int cc = gcol & 255;
          float sv = A.aff[grow] * W[4608 * 256 + cc]
                   + A.ppr[grow] * W[4609 * 256 + cc]
                   + A.trs[grow] * W[4610 * 256 + cc]
                   + A.sim[grow] * W[4611 * 256 + cc];
          float x = v + A.uq_in[n * 768 + gcol] + sv;
          A.h_out[grow * 512 + gcol] = f2bf(fmaxf(x, 0.f));
        } else {
          float b = (gcol < 128) ? A.wb2[gcol] : A.db2[gcol - 128];
          A.h_out[grow * 256 + gcol] = f2bf(fmaxf(v + b, 0.f));
        }
      }
    }
  }
}

// ---------------------------------------------------------------------------
// Finalize: layer-3 dots, masked softmax over K=32, prior, mu/sigma.
// ---------------------------------------------------------------------------
__global__ void finalize_k(const float* __restrict__ uq, const unsigned short* __restrict__ h2,
                           const float* __restrict__ w3, const float* __restrict__ wb3,
                           const float* __restrict__ d3, const float* __restrict__ db3,
                           const float* __restrict__ be2, const float* __restrict__ beb2,
                           const int* __restrict__ mask, const float* __restrict__ aff,
                           const float* __restrict__ lsg, float* __restrict__ out) {
  int n = blockIdx.x, t = threadIdx.x;
  __shared__ float s_logit[32], s_delta[32], s_red[4];
  // binding-encoder prior partial: relu(uq[n,512+t]) * be2[t]
  float x = uq[(size_t)n * 768 + 512 + t];
  float pp = fmaxf(x, 0.f) * be2[t];
  #pragma unroll
  for (int m = 32; m >= 1; m >>= 1) pp += __shfl_xor(pp, m);
  if ((t & 63) == 0) s_red[t >> 6] = pp;
  // layer-3: 8 threads per k
  int k = t >> 3, i8 = t & 7;
  const unsigned short* hr = h2 + ((size_t)n * 32 + k) * 256;
  float ls = 0.f, dl = 0.f;
  #pragma unroll
  for (int j = 0; j < 16; ++j) {
    int jj = i8 * 16 + j;
    ls += bf2f(hr[jj]) * w3[jj];
    dl += bf2f(hr[128 + jj]) * d3[jj];
  }
  #pragma unroll
  for (int m = 4; m >= 1; m >>= 1) { ls += __shfl_xor(ls, m); dl += __shfl_xor(dl, m); }
  if (i8 == 0) { s_logit[k] = ls + wb3[0]; s_delta[k] = dl + db3[0]; }
  __syncthreads();
  if (t < 64) {   // lanes 0..63 of wave 0; halves duplicate k = t&31
    int kk = t & 31;
    int m = mask[n * 32 + kk];
    float lg = m ? s_logit[kk] : -1e9f;
    float mx = lg;
    #pragma unroll
    for (int mm = 16; mm >= 1; mm >>= 1) mx = fmaxf(mx, __shfl_xor(mx, mm));
    float e = expf(lg - mx);
    float s = e;
    #pragma unroll
    for (int mm = 16; mm >= 1; mm >>= 1) s += __shfl_xor(s, mm);
    float wgt = (e / s) * (m ? 1.f : 0.f);
    float nrm = wgt;
    #pragma unroll
    for (int mm = 16; mm >= 1; mm >>= 1) nrm += __shfl_xor(nrm, mm);
    wgt = (nrm > 0.f) ? wgt / fmaxf(nrm, 1e-8f) : 0.f;
    float tr = wgt * aff[n * 32 + kk];
    float co = wgt * s_delta[kk];
    int am = m;
    #pragma unroll
    for (int mm = 16; mm >= 1; mm >>= 1) {
      tr += __shfl_xor(tr, mm);
      co += __shfl_xor(co, mm);
      am |= __shfl_xor(am, mm);
    }
    if (t == 0) {
      float prior = s_red[0] + s_red[1] + s_red[2] + s_red[3] + beb2[0] + 6.5f;
      float l0 = lsg[0];
      float sp = (l0 > 20.f) ? l0 : log1pf(expf(l0));
      float mu = am ? (tr + co) : prior;
      float sg = sp + (am ? 0.f : 0.15f) + 1e-4f;
      out[n] = mu;
      out[1024 + n] = sg;
    }
  }
}

// ---------------------------------------------------------------------------
extern "C" void kernel_launch(void* const* d_in, const int* in_sizes, int n_in,
                              void* d_out, int out_size, void* d_ws, size_t ws_size,
                              hipStream_t stream) {
  const float* np_ = (const float*)d_in[0];
  const float* nd_ = (const float*)d_in[1];
  const float* aff = (const float*)d_in[2];
  const float* ppr = (const float*)d_in[3];
  const float* trs = (const float*)d_in[4];
  const int*   msk = (const int*)d_in[5];
  const float* qp  = (const float*)d_in[6];
  const float* qd  = (const float*)d_in[7];
  const float* w1  = (const float*)d_in[8];
  const float* wb1 = (const float*)d_in[9];
  const float* w2  = (const float*)d_in[10];
  const float* wb2 = (const float*)d_in[11];
  const float* w3  = (const float*)d_in[12];
  const float* wb3 = (const float*)d_in[13];
  const float* d1  = (const float*)d_in[14];
  const float* db1 = (const float*)d_in[15];
  const float* d2  = (const float*)d_in[16];
  const float* db2 = (const float*)d_in[17];
  const float* d3  = (const float*)d_in[18];
  const float* db3 = (const float*)d_in[19];
  const float* be1 = (const float*)d_in[20];
  const float* beb1 = (const float*)d_in[21];
  const float* be2 = (const float*)d_in[22];
  const float* beb2 = (const float*)d_in[23];
  const float* lsg = (const float*)d_in[24];
  float* out = (float*)d_out;

  char* ws = (char*)d_ws;
  size_t off = 0;
  auto carve = [&](size_t bytes) -> void* {
    void* p = ws + off;
    off += (bytes + 511) & ~(size_t)511;
    return p;
  };
  float*          uq  = (float*)carve(1024ull * 768 * 4);
  unsigned short* h1  = (unsigned short*)carve(32768ull * 512 * 2);
  unsigned short* h2  = (unsigned short*)carve(32768ull * 256 * 2);
  unsigned short* Bt1 = (unsigned short*)carve(512ull * 1536 * 2);
  unsigned short* Btq = (unsigned short*)carve(768ull * 1536 * 2);
  unsigned short* Bt2 = (unsigned short*)carve(256ull * 512 * 2);
  unsigned short* Aq  = (unsigned short*)carve(1024ull * 1536 * 2);
  float*          sim = (float*)carve(32768ull * 4);
  float*          qn  = (float*)carve(1024ull * 4);
  (void)ws_size; (void)in_sizes; (void)n_in; (void)out_size;

  prepw_k<<<2048, 256, 0, stream>>>(w1, d1, be1, w2, d2, Bt1, Btq, Bt2);
  qprep_k<<<1024, 256, 0, stream>>>(qp, qd, Aq, qn);
  simk_k<<<8192, 256, 0, stream>>>(nd_, qd, qn, sim);

  GArgs g0{};
  g0.abf = Aq; g0.Bt = Btq; g0.uq_out = uq;
  g0.wb1 = wb1; g0.db1 = db1; g0.beb1 = beb1;
  gemm_k<0><<<dim3(8, 6), 256, 0, stream>>>(g0);

  GArgs g1{};
  g1.a1 = np_; g1.a2 = nd_; g1.Bt = Bt1;
  g1.uq_in = uq; g1.aff = aff; g1.ppr = ppr; g1.trs = trs; g1.sim = sim;
  g1.w1 = w1; g1.d1 = d1; g1.h_out = h1;
  gemm_k<1><<<dim3(256, 4), 256, 0, stream>>>(g1);

  GArgs g2{};
  g2.abf = h1; g2.Bt = Bt2; g2.wb2 = wb2; g2.db2 = db2; g2.h_out = h2;
  gemm_k<2><<<dim3(256, 2), 256, 0, stream>>>(g2);

  finalize_k<<<1024, 256, 0, stream>>>(uq, h2, w3, wb3, d3, db3, be2, beb2,
                                       msk, aff, lsg, out);
}

// Round 2
// 164.676 us; speedup vs baseline: 1.6993x; 1.6993x over previous
//
#include <hip/hip_runtime.h>
#include <cstdint>
#include <cstddef>

// ---------------------------------------------------------------------------
// NeighborTransferModel fused pipeline for MI355X (gfx950) — round 2
//
// Weight folding (as round 1): f@W1 = qp@(W[0:1024]+W[2048:3072])        (query)
//                                   + np@(W[1024:2048]-W[2048:3072])     (neighbor)
//                                   + qd@(W[3072:3584]+W[4096:4608])     (query)
//                                   + nd@(W[3584:4096]-W[4096:4608])     (neighbor)
//                                   + scalars@W[4608:4612]
// Round-2 changes:
//  * GEMM-1: BM=128 x BN=512 (full col panel) -> A (201 MB fp32) read ONCE.
//    8 waves, dbuf LDS (160 KB), A reg-staged fp32->bf16 swizzled ds_write,
//    B via global_load_lds w/ swizzle folded into per-lane global address.
//  * GEMM-2: BM=128 x BN=256 full-K, layer-3 dot fused into epilogue ->
//    writes logits/delta [32768] each; h2 never materialized.
// ---------------------------------------------------------------------------

typedef __attribute__((ext_vector_type(8))) short s16x8;
typedef __attribute__((ext_vector_type(4))) float f32x4;

static __device__ __forceinline__ unsigned short f2bf(float f) {
  unsigned u = __float_as_uint(f);
  u += 0x7fffu + ((u >> 16) & 1u);   // round-to-nearest-even
  return (unsigned short)(u >> 16);
}
static __device__ __forceinline__ float bf2f(unsigned short h) {
  return __uint_as_float(((unsigned)h) << 16);
}

static __device__ __forceinline__ void glds16(const void* g, void* l) {
  __builtin_amdgcn_global_load_lds(
      (const __attribute__((address_space(1))) void*)g,
      (__attribute__((address_space(3))) void*)l, 16, 0, 0);
}

// ---------------------------------------------------------------------------
// Weight-fold kernel (unchanged from round 1).
// ---------------------------------------------------------------------------
__global__ void prepw_k(const float* __restrict__ w1, const float* __restrict__ d1,
                        const float* __restrict__ be1, const float* __restrict__ w2,
                        const float* __restrict__ d2,
                        unsigned short* __restrict__ Bt1,
                        unsigned short* __restrict__ Btq,
                        unsigned short* __restrict__ Bt2) {
  const int NB1 = 512 * 1536, NBQ = 768 * 1536, NB2 = 256 * 512;
  for (int idx = blockIdx.x * 256 + threadIdx.x; idx < NB1 + NBQ + NB2;
       idx += gridDim.x * 256) {
    if (idx < NB1) {
      int c = idx / 1536, j = idx - c * 1536;
      const float* W = (c < 256) ? w1 : d1;
      int cc = c & 255;
      float v;
      if (j < 1024) v = W[(1024 + j) * 256 + cc] - W[(2048 + j) * 256 + cc];
      else { int jd = j - 1024; v = W[(3584 + jd) * 256 + cc] - W[(4096 + jd) * 256 + cc]; }
      Bt1[idx] = f2bf(v);
    } else if (idx < NB1 + NBQ) {
      int i2 = idx - NB1;
      int c = i2 / 1536, j = i2 - c * 1536;
      float v;
      if (c < 512) {
        const float* W = (c < 256) ? w1 : d1;
        int cc = c & 255;
        if (j < 1024) v = W[j * 256 + cc] + W[(2048 + j) * 256 + cc];
        else { int jd = j - 1024; v = W[(3072 + jd) * 256 + cc] + W[(4096 + jd) * 256 + cc]; }
      } else {
        v = be1[j * 256 + (c - 512)];
      }
      Btq[i2] = f2bf(v);
    } else {
      int i2 = idx - NB1 - NBQ;
      int c = i2 / 512, j = i2 - c * 512;
      float v = 0.f;
      if (c < 128 && j < 256) v = w2[j * 128 + c];
      else if (c >= 128 && j >= 256) v = d2[(j - 256) * 128 + (c - 128)];
      Bt2[i2] = f2bf(v);
    }
  }
}

// ---------------------------------------------------------------------------
// Query prep (unchanged): Aq bf16 [1024][1536] = [qp | qd], qn = ||qd||
// ---------------------------------------------------------------------------
__global__ void qprep_k(const float* __restrict__ qp, const float* __restrict__ qd,
                        unsigned short* __restrict__ Aq, float* __restrict__ qn) {
  int n = blockIdx.x, t = threadIdx.x;
  const float4* qp4 = (const float4*)(qp + (size_t)n * 1024);
  float4 v = qp4[t];
  ushort4 o4;
  o4.x = f2bf(v.x); o4.y = f2bf(v.y); o4.z = f2bf(v.z); o4.w = f2bf(v.w);
  *(ushort4*)(Aq + (size_t)n * 1536 + t * 4) = o4;
  const float2* qd2 = (const float2*)(qd + (size_t)n * 512);
  float2 w = qd2[t];
  ushort2 o2; o2.x = f2bf(w.x); o2.y = f2bf(w.y);
  *(ushort2*)(Aq + (size_t)n * 1536 + 1024 + t * 2) = o2;
  float ss = w.x * w.x + w.y * w.y;
  #pragma unroll
  for (int m = 32; m >= 1; m >>= 1) ss += __shfl_xor(ss, m);
  __shared__ float sr[4];
  if ((t & 63) == 0) sr[t >> 6] = ss;
  __syncthreads();
  if (t == 0) qn[n] = sqrtf(sr[0] + sr[1] + sr[2] + sr[3]);
}

// ---------------------------------------------------------------------------
// Cosine similarity (unchanged)
// ---------------------------------------------------------------------------
__global__ void simk_k(const float* __restrict__ nd, const float* __restrict__ qd,
                       const float* __restrict__ qn, float* __restrict__ sim) {
  int r = blockIdx.x * 4 + (threadIdx.x >> 6);
  int l = threadIdx.x & 63;
  int n = r >> 5;
  const float4* a = (const float4*)(nd + (size_t)r * 512);
  const float4* b = (const float4*)(qd + (size_t)n * 512);
  float dot = 0.f, ns = 0.f;
  #pragma unroll
  for (int j = 0; j < 2; ++j) {
    float4 x = a[l + 64 * j], y = b[l + 64 * j];
    dot += x.x * y.x + x.y * y.y + x.z * y.z + x.w * y.w;
    ns  += x.x * x.x + x.y * x.y + x.z * x.z + x.w * x.w;
  }
  #pragma unroll
  for (int m = 32; m >= 1; m >>= 1) { dot += __shfl_xor(dot, m); ns += __shfl_xor(ns, m); }
  if (l == 0) sim[r] = dot / (fmaxf(qn[n], 1e-8f) * fmaxf(sqrtf(ns), 1e-8f));
}

// ---------------------------------------------------------------------------
// GEMM-0: query GEMM, 128x128 tile (round-1 structure, MODE0 only).
// M=1024, Kd=1536, NC=768.  uq[n][c] = Aq @ Btq^T + bias
// ---------------------------------------------------------------------------
__global__ __launch_bounds__(256) void gemm0_k(
    const unsigned short* __restrict__ abf, const unsigned short* __restrict__ Bt,
    const float* __restrict__ wb1, const float* __restrict__ db1,
    const float* __restrict__ beb1, float* __restrict__ uq_out) {
  __shared__ short As[128 * 64];
  __shared__ short Bs[128 * 64];
  const int tid = threadIdx.x;
  const int l = tid & 63, w = tid >> 6;
  const int wr = w >> 1, wc = w & 1;
  const int br = blockIdx.x, bc = blockIdx.y;
  const int c0 = bc * 128;
  f32x4 acc[4][4] = {};

  for (int kt = 0; kt < 24; ++kt) {
    const int k0 = kt * 64;
    __syncthreads();
    #pragma unroll
    for (int rep = 0; rep < 4; ++rep) {
      int q = rep * 256 + tid;
      int row = q >> 3, slot = q & 7;
      int kc = slot ^ (row & 7);
      int gk = k0 + kc * 8;
      long grow = (long)br * 128 + row;
      s16x8 pk = *(const s16x8*)(abf + grow * 1536 + gk);
      *(s16x8*)(&As[q * 8]) = pk;
      s16x8 pb = *(const s16x8*)(Bt + (long)(c0 + row) * 1536 + gk);
      *(s16x8*)(&Bs[q * 8]) = pb;
    }
    __syncthreads();
    #pragma unroll
    for (int kh = 0; kh < 2; ++kh) {
      s16x8 af[4], bfr[4];
      #pragma unroll
      for (int mi = 0; mi < 4; ++mi) {
        int ra = wr * 64 + mi * 16 + (l & 15);
        int sidx = (kh * 4 + (l >> 4)) ^ (ra & 7);
        af[mi] = *(const s16x8*)(&As[ra * 64 + sidx * 8]);
      }
      #pragma unroll
      for (int ni = 0; ni < 4; ++ni) {
        int rb = wc * 64 + ni * 16 + (l & 15);
        int sidx = (kh * 4 + (l >> 4)) ^ (rb & 7);
        bfr[ni] = *(const s16x8*)(&Bs[rb * 64 + sidx * 8]);
      }
      #pragma unroll
      for (int mi = 0; mi < 4; ++mi)
        #pragma unroll
        for (int ni = 0; ni < 4; ++ni)
          acc[mi][ni] = __builtin_amdgcn_mfma_f32_16x16x32_bf16(
              af[mi], bfr[ni], acc[mi][ni], 0, 0, 0);
    }
  }
  #pragma unroll
  for (int mi = 0; mi < 4; ++mi)
    #pragma unroll
    for (int ni = 0; ni < 4; ++ni)
      #pragma unroll
      for (int r = 0; r < 4; ++r) {
        int rowl = wr * 64 + mi * 16 + (l >> 4) * 4 + r;
        int coll = wc * 64 + ni * 16 + (l & 15);
        long grow = (long)br * 128 + rowl;
        int gcol = c0 + coll;
        float b = (gcol < 256) ? wb1[gcol]
                 : (gcol < 512) ? db1[gcol - 256] : beb1[gcol - 512];
        uq_out[grow * 768 + gcol] = acc[mi][ni][r] + b;
      }
}

// ---------------------------------------------------------------------------
// GEMM-1: neighbor GEMM.  BM=128, BN=512 (full panel), BK=64, dbuf 160KB LDS,
// 8 waves (2M x 4N, each 64x128).  A fp32 read once, cast->bf16 on the fly.
// Epilogue: h1 = relu(acc + uq + aff*S0 + ppr*S1 + trust*S2 + sim*S3)
// ---------------------------------------------------------------------------
__global__ __launch_bounds__(512, 2) void gemm1_k(
    const float* __restrict__ Anp, const float* __restrict__ And,
    const unsigned short* __restrict__ Bt,
    const float* __restrict__ uq, const float* __restrict__ aff,
    const float* __restrict__ ppr, const float* __restrict__ trs,
    const float* __restrict__ sim, const float* __restrict__ w1,
    const float* __restrict__ d1, unsigned short* __restrict__ h1) {
  __shared__ short As[2][128 * 64];   // 16 KB x2
  __shared__ short Bs[2][512 * 64];   // 64 KB x2  -> 160 KB total
  const int tid = threadIdx.x;
  const int l = tid & 63, w = tid >> 6;
  const int wr = w >> 2, wc = w & 3;
  const long br = blockIdx.x;
  const int arow = tid >> 2, aseg = tid & 3;
  const long agrow = br * 128 + arow;

  f32x4 acc[4][8] = {};
  float areg[16];

  const int brow = (tid >> 3), bslot = tid & 7;   // B staging decomposition

  // ---- staging helpers ----
  auto stageB = [&](int buf, int kt) {
    const int k0 = kt * 64;
    #pragma unroll
    for (int i = 0; i < 8; ++i) {
      int row = i * 64 + brow;
      const unsigned short* src =
          Bt + (size_t)row * 1536 + k0 + ((bslot ^ (row & 7)) * 8);
      glds16(src, &Bs[buf][(i * 512 + tid) * 8]);
    }
  };
  auto loadA = [&](int kt) {
    const int k0 = kt * 64 + aseg * 16;
    const float* src = (k0 < 1024) ? (Anp + agrow * 1024 + k0)
                                   : (And + agrow * 512 + (k0 - 1024));
    #pragma unroll
    for (int i = 0; i < 4; ++i) {
      float4 v = ((const float4*)src)[i];
      areg[i * 4 + 0] = v.x; areg[i * 4 + 1] = v.y;
      areg[i * 4 + 2] = v.z; areg[i * 4 + 3] = v.w;
    }
  };
  auto writeA = [&](int buf) {
    #pragma unroll
    for (int j = 0; j < 2; ++j) {
      int slot = (aseg * 2 + j) ^ (arow & 7);
      s16x8 pk;
      #pragma unroll
      for (int e = 0; e < 8; ++e) pk[e] = (short)f2bf(areg[j * 8 + e]);
      *(s16x8*)(&As[buf][arow * 64 + slot * 8]) = pk;
    }
  };

  // ---- prologue ----
  stageB(0, 0);
  loadA(0);
  writeA(0);
  __syncthreads();

  for (int kt = 0; kt < 24; ++kt) {
    const int cur = kt & 1, nxt = cur ^ 1;
    if (kt < 23) { stageB(nxt, kt + 1); loadA(kt + 1); }
    #pragma unroll
    for (int kh = 0; kh < 2; ++kh) {
      s16x8 af[4], bfr[8];
      #pragma unroll
      for (int mi = 0; mi < 4; ++mi) {
        int ra = wr * 64 + mi * 16 + (l & 15);
        int sl = (kh * 4 + (l >> 4)) ^ (ra & 7);
        af[mi] = *(const s16x8*)(&As[cur][ra * 64 + sl * 8]);
      }
      #pragma unroll
      for (int ni = 0; ni < 8; ++ni) {
        int rb = wc * 128 + ni * 16 + (l & 15);
        int sl = (kh * 4 + (l >> 4)) ^ (rb & 7);
        bfr[ni] = *(const s16x8*)(&Bs[cur][rb * 64 + sl * 8]);
      }
      #pragma unroll
      for (int mi = 0; mi < 4; ++mi)
        #pragma unroll
        for (int ni = 0; ni < 8; ++ni)
          acc[mi][ni] = __builtin_amdgcn_mfma_f32_16x16x32_bf16(
              af[mi], bfr[ni], acc[mi][ni], 0, 0, 0);
    }
    if (kt < 23) writeA(nxt);
    __syncthreads();
  }

  // ---- epilogue ----
  #pragma unroll
  for (int mi = 0; mi < 4; ++mi) {
    #pragma unroll
    for (int r = 0; r < 4; ++r) {
      int rowl = wr * 64 + mi * 16 + (l >> 4) * 4 + r;
      long grow = br * 128 + rowl;
      float sa = aff[grow], sp = ppr[grow], st = trs[grow], ss = sim[grow];
      long n = grow >> 5;
      #pragma unroll
      for (int ni = 0; ni < 8; ++ni) {
        int gcol = wc * 128 + ni * 16 + (l & 15);
        const float* W = (gcol < 256) ? w1 : d1;
        int cc = gcol & 255;
        float sv = sa * W[4608 * 256 + cc] + sp * W[4609 * 256 + cc]
                 + st * W[4610 * 256 + cc] + ss * W[4611 * 256 + cc];
        float x = acc[mi][ni][r] + uq[n * 768 + gcol] + sv;
        h1[grow * 512 + gcol] = f2bf(fmaxf(x, 0.f));
      }
    }
  }
}

// ---------------------------------------------------------------------------
// GEMM-2 + fused layer-3:  BM=128, NC=256, Kd=512 full.  8 waves (2M x 4N,
// each 64x64).  All staging via global_load_lds (A=h1 bf16, B=Bt2 bf16).
// Epilogue: h2 = relu(acc+b2); logits = h2[:,0:128]@w3 + wb3;
//           delta = h2[:,128:256]@d3 + db3  -> ld[grow], ld[32768+grow]
// ---------------------------------------------------------------------------
__global__ __launch_bounds__(512, 2) void gemm2_k(
    const unsigned short* __restrict__ h1, const unsigned short* __restrict__ Bt2,
    const float* __restrict__ wb2, const float* __restrict__ db2,
    const float* __restrict__ w3, const float* __restrict__ wb3,
    const float* __restrict__ d3, const float* __restrict__ db3,
    float* __restrict__ ld) {
  __shared__ short As[2][128 * 64];   // 16 KB x2
  __shared__ short Bs[2][256 * 64];   // 32 KB x2
  __shared__ float part[4][128];
  const int tid = threadIdx.x;
  const int l = tid & 63, w = tid >> 6;
  const int wr = w >> 2, wc = w & 3;
  const long br = blockIdx.x;
  const int srow = tid >> 3, sslot = tid & 7;

  f32x4 acc[4][4] = {};

  auto stageA = [&](int buf, int kt) {
    const int k0 = kt * 64;
    #pragma unroll
    for (int i = 0; i < 2; ++i) {
      int row = i * 64 + srow;
      const unsigned short* src =
          h1 + (br * 128 + row) * 512 + k0 + ((sslot ^ (row & 7)) * 8);
      glds16(src, &As[buf][(i * 512 + tid) * 8]);
    }
  };
  auto stageB = [&](int buf, int kt) {
    const int k0 = kt * 64;
    #pragma unroll
    for (int i = 0; i < 4; ++i) {
      int row = i * 64 + srow;
      const unsigned short* src =
          Bt2 + (size_t)row * 512 + k0 + ((sslot ^ (row & 7)) * 8);
      glds16(src, &Bs[buf][(i * 512 + tid) * 8]);
    }
  };

  stageA(0, 0); stageB(0, 0);
  __syncthreads();

  for (int kt = 0; kt < 8; ++kt) {
    const int cur = kt & 1, nxt = cur ^ 1;
    if (kt < 7) { stageA(nxt, kt + 1); stageB(nxt, kt + 1); }
    #pragma unroll
    for (int kh = 0; kh < 2; ++kh) {
      s16x8 af[4], bfr[4];
      #pragma unroll
      for (int mi = 0; mi < 4; ++mi) {
        int ra = wr * 64 + mi * 16 + (l & 15);
        int sl = (kh * 4 + (l >> 4)) ^ (ra & 7);
        af[mi] = *(const s16x8*)(&As[cur][ra * 64 + sl * 8]);
      }
      #pragma unroll
      for (int ni = 0; ni < 4; ++ni) {
        int rb = wc * 64 + ni * 16 + (l & 15);
        int sl = (kh * 4 + (l >> 4)) ^ (rb & 7);
        bfr[ni] = *(const s16x8*)(&Bs[cur][rb * 64 + sl * 8]);
      }
      #pragma unroll
      for (int mi = 0; mi < 4; ++mi)
        #pragma unroll
        for (int ni = 0; ni < 4; ++ni)
          acc[mi][ni] = __builtin_amdgcn_mfma_f32_16x16x32_bf16(
              af[mi], bfr[ni], acc[mi][ni], 0, 0, 0);
    }
    __syncthreads();
  }

  // ---- fused layer-2 bias/relu + layer-3 dot ----
  float coef[4], b2[4];
  #pragma unroll
  for (int ni = 0; ni < 4; ++ni) {
    int col = wc * 64 + ni * 16 + (l & 15);
    coef[ni] = (col < 128) ? w3[col] : d3[col - 128];
    b2[ni]   = (col < 128) ? wb2[col] : db2[col - 128];
  }
  #pragma unroll
  for (int mi = 0; mi < 4; ++mi) {
    #pragma unroll
    for (int rr = 0; rr < 4; ++rr) {
      float p = 0.f;
      #pragma unroll
      for (int ni = 0; ni < 4; ++ni) {
        float x = fmaxf(acc[mi][ni][rr] + b2[ni], 0.f);
        p += x * coef[ni];
      }
      #pragma unroll
      for (int m = 1; m <= 8; m <<= 1) p += __shfl_xor(p, m);
      if ((l & 15) == 0)
        part[wc][wr * 64 + mi * 16 + (l >> 4) * 4 + rr] = p;
    }
  }
  __syncthreads();
  if (tid < 256) {
    int row = tid >> 1, hf = tid & 1;
    long grow = br * 128 + row;
    float v = hf ? (part[2][row] + part[3][row] + db3[0])
                 : (part[0][row] + part[1][row] + wb3[0]);
    ld[(size_t)hf * 32768 + grow] = v;
  }
}

// ---------------------------------------------------------------------------
// Finalize: masked softmax over K=32, prior, mu/sigma.
// ---------------------------------------------------------------------------
__global__ void finalize2_k(const float* __restrict__ uq, const float* __restrict__ ld,
                            const float* __restrict__ be2, const float* __restrict__ beb2,
                            const int* __restrict__ mask, const float* __restrict__ aff,
                            const float* __restrict__ lsg, float* __restrict__ out) {
  int n = blockIdx.x, t = threadIdx.x;
  __shared__ float s_red[4];
  float x = uq[(size_t)n * 768 + 512 + t];
  float pp = fmaxf(x, 0.f) * be2[t];
  #pragma unroll
  for (int m = 32; m >= 1; m >>= 1) pp += __shfl_xor(pp, m);
  if ((t & 63) == 0) s_red[t >> 6] = pp;
  __syncthreads();
  if (t < 64) {
    int kk = t & 31;
    int m = mask[n * 32 + kk];
    float lg = m ? ld[n * 32 + kk] : -1e9f;
    float dl = ld[32768 + n * 32 + kk];
    float mx = lg;
    #pragma unroll
    for (int mm = 16; mm >= 1; mm >>= 1) mx = fmaxf(mx, __shfl_xor(mx, mm));
    float e = expf(lg - mx);
    float s = e;
    #pragma unroll
    for (int mm = 16; mm >= 1; mm >>= 1) s += __shfl_xor(s, mm);
    float wgt = (e / s) * (m ? 1.f : 0.f);
    float nrm = wgt;
    #pragma unroll
    for (int mm = 16; mm >= 1; mm >>= 1) nrm += __shfl_xor(nrm, mm);
    wgt = (nrm > 0.f) ? wgt / fmaxf(nrm, 1e-8f) : 0.f;
    float tr = wgt * aff[n * 32 + kk];
    float co = wgt * dl;
    int am = m;
    #pragma unroll
    for (int mm = 16; mm >= 1; mm >>= 1) {
      tr += __shfl_xor(tr, mm);
      co += __shfl_xor(co, mm);
      am |= __shfl_xor(am, mm);
    }
    if (t == 0) {
      float prior = s_red[0] + s_red[1] + s_red[2] + s_red[3] + beb2[0] + 6.5f;
      float l0 = lsg[0];
      float sp = (l0 > 20.f) ? l0 : log1pf(expf(l0));
      float mu = am ? (tr + co) : prior;
      float sg = sp + (am ? 0.f : 0.15f) + 1e-4f;
      out[n] = mu;
      out[1024 + n] = sg;
    }
  }
}

// ---------------------------------------------------------------------------
extern "C" void kernel_launch(void* const* d_in, const int* in_sizes, int n_in,
                              void* d_out, int out_size, void* d_ws, size_t ws_size,
                              hipStream_t stream) {
  const float* np_ = (const float*)d_in[0];
  const float* nd_ = (const float*)d_in[1];
  const float* aff = (const float*)d_in[2];
  const float* ppr = (const float*)d_in[3];
  const float* trs = (const float*)d_in[4];
  const int*   msk = (const int*)d_in[5];
  const float* qp  = (const float*)d_in[6];
  const float* qd  = (const float*)d_in[7];
  const float* w1  = (const float*)d_in[8];
  const float* wb1 = (const float*)d_in[9];
  const float* w2  = (const float*)d_in[10];
  const float* wb2 = (const float*)d_in[11];
  const float* w3  = (const float*)d_in[12];
  const float* wb3 = (const float*)d_in[13];
  const float* d1  = (const float*)d_in[14];
  const float* db1 = (const float*)d_in[15];
  const float* d2  = (const float*)d_in[16];
  const float* db2 = (const float*)d_in[17];
  const float* d3  = (const float*)d_in[18];
  const float* db3 = (const float*)d_in[19];
  const float* be1 = (const float*)d_in[20];
  const float* beb1 = (const float*)d_in[21];
  const float* be2 = (const float*)d_in[22];
  const float* beb2 = (const float*)d_in[23];
  const float* lsg = (const float*)d_in[24];
  float* out = (float*)d_out;

  char* ws = (char*)d_ws;
  size_t off = 0;
  auto carve = [&](size_t bytes) -> void* {
    void* p = ws + off;
    off += (bytes + 511) & ~(size_t)511;
    return p;
  };
  float*          uq  = (float*)carve(1024ull * 768 * 4);
  unsigned short* h1  = (unsigned short*)carve(32768ull * 512 * 2);
  float*          ld  = (float*)carve(2ull * 32768 * 4);
  unsigned short* Bt1 = (unsigned short*)carve(512ull * 1536 * 2);
  unsigned short* Btq = (unsigned short*)carve(768ull * 1536 * 2);
  unsigned short* Bt2 = (unsigned short*)carve(256ull * 512 * 2);
  unsigned short* Aq  = (unsigned short*)carve(1024ull * 1536 * 2);
  float*          sim = (float*)carve(32768ull * 4);
  float*          qn  = (float*)carve(1024ull * 4);
  (void)ws_size; (void)in_sizes; (void)n_in; (void)out_size;

  prepw_k<<<2048, 256, 0, stream>>>(w1, d1, be1, w2, d2, Bt1, Btq, Bt2);
  qprep_k<<<1024, 256, 0, stream>>>(qp, qd, Aq, qn);
  simk_k<<<8192, 256, 0, stream>>>(nd_, qd, qn, sim);

  gemm0_k<<<dim3(8, 6), 256, 0, stream>>>(Aq, Btq, wb1, db1, beb1, uq);

  gemm1_k<<<256, 512, 0, stream>>>(np_, nd_, Bt1, uq, aff, ppr, trs, sim,
                                   w1, d1, h1);

  gemm2_k<<<256, 512, 0, stream>>>(h1, Bt2, wb2, db2, w3, wb3, d3, db3, ld);

  finalize2_k<<<1024, 256, 0, stream>>>(uq, ld, be2, beb2, msk, aff, lsg, out);
}